// Round 21
// baseline (54.122 us; speedup 1.0000x reference)
//
#include <hip/hip_runtime.h>
#include <hip/hip_bf16.h>

typedef __attribute__((ext_vector_type(8)))  short short8;
typedef __attribute__((ext_vector_type(4)))  float f32x4;
typedef __attribute__((ext_vector_type(16))) float f32x16;

#define CIN   16
#define HH    256
#define WW    256
#define OHH   254
#define OWW   254
#define HW    (HH * WW)

// LDS row-ring: [2 cihalf][16 slot][36 w][8 ci] bf16, 16B cells (R7/R13-proven
// geometry: px stride 16B -> conflict-free b128). Half stride padded +16B.
#define SLOTU  (36 * 8)              // 288 ushorts per patch row
#define HALF_R (16 * SLOTU + 8)      // 4616 ushorts per ci-half

__device__ __forceinline__ ushort f2bf(float f) {
    unsigned u = __builtin_bit_cast(unsigned, f);
    unsigned r = (u + 0x7fffu + ((u >> 16) & 1u)) >> 16;
    return (ushort)r;
}

// fast tanh(tanh(x)): exp2-based (verified absmax 3.9e-3 in R1-R20)
__device__ __forceinline__ float dtanh2(float x) {
    const float K = 2.8853900817779268f;   // 2*log2(e)
    float xc = fminf(fmaxf(x, -9.0f), 9.0f);
    float e1 = __builtin_amdgcn_exp2f(K * xc);
    float t1 = 1.0f - 2.0f * __builtin_amdgcn_rcpf(e1 + 1.0f);
    float e2 = __builtin_amdgcn_exp2f(K * t1);
    return 1.0f - 2.0f * __builtin_amdgcn_rcpf(e2 + 1.0f);
}

// tree min over 16 accumulator elements (depth 4)
__device__ __forceinline__ float rmin16(f32x16 a) {
    float t0 = fminf(fminf(a[0],  a[1]),  fminf(a[2],  a[3]));
    float t1 = fminf(fminf(a[4],  a[5]),  fminf(a[6],  a[7]));
    float t2 = fminf(fminf(a[8],  a[9]),  fminf(a[10], a[11]));
    float t3 = fminf(fminf(a[12], a[13]), fminf(a[14], a[15]));
    return fminf(fminf(t0, t1), fminf(t2, t3));
}

// Weights fp32 OIHW [64][16][3][3] -> 32x32x16 A-fragments (R9-proven):
// wfrag[tap][j][lane][r]: channel row = j*32+(lane&31), ci = 8*(lane>>5)+r.
__global__ void prep_weights(const float* __restrict__ wsrc, ushort* __restrict__ wfrag) {
    int idx = blockIdx.x * 256 + threadIdx.x;
    if (idx >= 9216) return;
    int r    = idx & 7;
    int lane = (idx >> 3) & 63;
    int j    = (idx >> 9) & 1;
    int tap  = idx >> 10;                 // 0..8
    int ci   = 8 * (lane >> 5) + r;
    int co   = j * 32 + (lane & 31);
    int kh   = tap / 3, kw = tap - 3 * kh;
    wfrag[idx] = f2bf(wsrc[(co * CIN + ci) * 9 + kh * 3 + kw]);
}

// 85-row strips x 3 = 768 blocks = EXACTLY 3/CU zero-tail (12 waves/CU).
// Strips overlap 3% (rows 85-87/170-172 computed twice -> identical duplicate
// stores, benign). 2-deep parity prefetch (vmcnt(4)) + raw s_barrier, lgkm-only.
// Live ~148 regs at (256,3)=170 cap; R2/R6/R10: never cap below the set.
__global__ __launch_bounds__(256, 3) void conv_min_tanh(
        const float* __restrict__ x, const ushort* __restrict__ wfrag,
        const float* __restrict__ bias, float* __restrict__ out) {
    __shared__ ushort ring[2 * HALF_R];      // 18,464 B
    __shared__ ushort mp[2][2][4][32];       // 1,024 B (parity-double-buffered)

    const int tid   = threadIdx.x;
    const int ow0   = blockIdx.x * 32;
    const int hbase = blockIdx.y * 85;       // strip base row (0, 85, 170)
    const int n     = blockIdx.z;
    const float* xb = x + (size_t)n * CIN * HW;

    // ---- prologue: stage patch rows hbase..hbase+7 (chunks 0,1) inline ----
    auto stage_inline = [&](int pos) {       // pos = lr*36 + ciq*9 + w4, lr 0..7
        int lr_  = pos / 36;
        int rm_  = pos - lr_ * 36;
        int ciq_ = rm_ / 9;
        int w4_  = rm_ - ciq_ * 9;
        int hg  = min(hbase + lr_, HH - 1);
        int wg_ = min(ow0 + 4 * w4_, WW - 4);
        const float* src = xb + (size_t)(ciq_ * 4) * HW + hg * WW + wg_;
        f32x4 v0 = *reinterpret_cast<const f32x4*>(src);
        f32x4 v1 = *reinterpret_cast<const f32x4*>(src + HW);
        f32x4 v2 = *reinterpret_cast<const f32x4*>(src + 2 * HW);
        f32x4 v3 = *reinterpret_cast<const f32x4*>(src + 3 * HW);
        ushort* dst = &ring[(ciq_ >> 1) * HALF_R + lr_ * SLOTU + (4 * w4_) * 8 + (ciq_ & 1) * 4];
#pragma unroll
        for (int e = 0; e < 4; ++e) {
            unsigned lo, hi;
            asm("v_cvt_pk_bf16_f32 %0, %1, %2" : "=v"(lo) : "v"(v0[e]), "v"(v1[e]));
            asm("v_cvt_pk_bf16_f32 %0, %1, %2" : "=v"(hi) : "v"(v2[e]), "v"(v3[e]));
            uint2 pk; pk.x = lo; pk.y = hi;
            *reinterpret_cast<uint2*>(dst + e * 8) = pk;
        }
    };
    stage_inline(tid);
    if (tid < 32) stage_inline(tid + 256);   // 288 positions = rel rows 0..7

    // ---- steady-state stage constants (threads 0..143, 1 position each) ----
    const bool sa = (tid < 144);
    const int lr  = tid / 36;                // 0..3 within chunk
    const int rm  = tid - lr * 36;
    const int ciq = rm / 9;
    const int w4  = rm - ciq * 9;
    const int wg  = min(ow0 + 4 * w4, WW - 4);
    const float* gbase = xb + (size_t)(ciq * 4) * HW + wg;
    ushort* sdst = &ring[(ciq >> 1) * HALF_R + (4 * w4) * 8 + (ciq & 1) * 4];

    f32x4 ra0 = {}, ra1 = {}, ra2 = {}, ra3 = {};
    f32x4 rb0 = {}, rb1 = {}, rb2 = {}, rb3 = {};

#define ISSUE(cc, r0, r1, r2, r3)                                              \
    if (sa) {                                                                  \
        int hg = min(hbase + 4 * (cc) + lr, HH - 1);                           \
        const float* s_ = gbase + hg * WW;                                     \
        asm volatile("global_load_dwordx4 %0, %1, off" : "=v"(r0) : "v"(s_) : "memory");           \
        asm volatile("global_load_dwordx4 %0, %1, off" : "=v"(r1) : "v"(s_ + HW) : "memory");      \
        asm volatile("global_load_dwordx4 %0, %1, off" : "=v"(r2) : "v"(s_ + 2 * HW) : "memory");  \
        asm volatile("global_load_dwordx4 %0, %1, off" : "=v"(r3) : "v"(s_ + 3 * HW) : "memory");  \
    }

#define WRITEBK(cc, r0, r1, r2, r3)                                            \
    if (sa) {                                                                  \
        ushort* d_ = sdst + ((4 * (cc) + lr) & 15) * SLOTU;                    \
        _Pragma("unroll")                                                      \
        for (int e = 0; e < 4; ++e) {                                          \
            unsigned lo_, hi_;                                                 \
            asm("v_cvt_pk_bf16_f32 %0, %1, %2" : "=v"(lo_) : "v"(r0[e]), "v"(r1[e]));  \
            asm("v_cvt_pk_bf16_f32 %0, %1, %2" : "=v"(hi_) : "v"(r2[e]), "v"(r3[e]));  \
            uint2 pk_; pk_.x = lo_; pk_.y = hi_;                               \
            *reinterpret_cast<uint2*>(d_ + e * 8) = pk_;                       \
        }                                                                      \
    }

    ISSUE(2, ra0, ra1, ra2, ra3);            // 2-deep prefetch, 8 loads in flight
    ISSUE(3, rb0, rb1, rb2, rb3);

    // ---- weights (A-operand) + bias while loads fly ----
    const int lane  = tid & 63;
    const int wid   = tid >> 6;
    const int jw    = wid & 1;               // channel tile
    const int rq    = wid >> 1;              // row pair within chunk
    const int px    = lane & 31;
    const int khalf = lane >> 5;
    short8 wf[9];
#pragma unroll
    for (int tap = 0; tap < 9; ++tap)
        wf[tap] = *reinterpret_cast<const short8*>(wfrag + ((tap * 2 + jw) * 64 + lane) * 8);
    f32x16 bi;                               // D row = (r&3)+8*(r>>2)+4*khalf
#pragma unroll
    for (int q4 = 0; q4 < 4; ++q4) {
        f32x4 b = *reinterpret_cast<const f32x4*>(bias + jw * 32 + 4 * khalf + 8 * q4);
#pragma unroll
        for (int s = 0; s < 4; ++s) bi[q4 * 4 + s] = b[s];
    }
    const ushort* bptr = &ring[khalf * HALF_R + px * 8];

    asm volatile("s_waitcnt lgkmcnt(0)" ::: "memory");
    __builtin_amdgcn_s_barrier();            // rel rows 0..7 ready; loads in flight

    // ---- 22 chunks: compute(c) | vmcnt(4) write(c+2) issue(c+4) | barrier | out ----
#pragma unroll 2
    for (int c = 0; c < 22; ++c) {
        // merged-row compute: rel rows R0=4c+2rq, R0+1; 4 patch rows, 12 reads, 18 MFMA
        {
            const int R0 = 4 * c + 2 * rq;
            f32x16 a0 = bi, a1 = bi;
#pragma unroll
            for (int t = 0; t < 4; ++t) {
                const ushort* rp = bptr + ((R0 + t) & 15) * SLOTU;
                short8 f0 = *reinterpret_cast<const short8*>(rp);
                short8 f1 = *reinterpret_cast<const short8*>(rp + 8);
                short8 f2 = *reinterpret_cast<const short8*>(rp + 16);
                if (t < 3) {
                    a0 = __builtin_amdgcn_mfma_f32_32x32x16_bf16(wf[t * 3 + 0], f0, a0, 0, 0, 0);
                    a0 = __builtin_amdgcn_mfma_f32_32x32x16_bf16(wf[t * 3 + 1], f1, a0, 0, 0, 0);
                    a0 = __builtin_amdgcn_mfma_f32_32x32x16_bf16(wf[t * 3 + 2], f2, a0, 0, 0, 0);
                }
                if (t >= 1) {
                    a1 = __builtin_amdgcn_mfma_f32_32x32x16_bf16(wf[(t - 1) * 3 + 0], f0, a1, 0, 0, 0);
                    a1 = __builtin_amdgcn_mfma_f32_32x32x16_bf16(wf[(t - 1) * 3 + 1], f1, a1, 0, 0, 0);
                    a1 = __builtin_amdgcn_mfma_f32_32x32x16_bf16(wf[(t - 1) * 3 + 2], f2, a1, 0, 0, 0);
                }
            }
            float v0 = rmin16(a0), v1 = rmin16(a1);
            v0 = fminf(v0, __shfl_xor(v0, 32, 64));
            v1 = fminf(v1, __shfl_xor(v1, 32, 64));
            if (lane < 32) {
                mp[c & 1][jw][2 * rq + 0][px] = f2bf(v0);
                mp[c & 1][jw][2 * rq + 1][px] = f2bf(v1);
            }
        }

        // drain ONLY the oldest chunk (counted vmcnt), write it, reissue (parity)
        if (c < 21) {
            if ((c & 1) == 0) {
                asm volatile("s_waitcnt vmcnt(4)"
                             : "+v"(ra0), "+v"(ra1), "+v"(ra2), "+v"(ra3) :: "memory");
                WRITEBK(c + 2, ra0, ra1, ra2, ra3);
                ISSUE(min(c + 4, 22), ra0, ra1, ra2, ra3);
            } else {
                asm volatile("s_waitcnt vmcnt(4)"
                             : "+v"(rb0), "+v"(rb1), "+v"(rb2), "+v"(rb3) :: "memory");
                WRITEBK(c + 2, rb0, rb1, rb2, rb3);
                ISSUE(min(c + 4, 22), rb0, rb1, rb2, rb3);
            }
        }

        asm volatile("s_waitcnt lgkmcnt(0)" ::: "memory");
        __builtin_amdgcn_s_barrier();        // NO vmcnt drain: prefetch survives

        // out(c): threads 0..127, one pixel each; mp parity c&1.
        // Strip overlap rows are written twice with identical values (benign).
        if (tid < 128) {
            const int r4 = tid >> 5, opx = tid & 31;
            float f0 = __builtin_bit_cast(float, (unsigned)mp[c & 1][0][r4][opx] << 16);
            float f1 = __builtin_bit_cast(float, (unsigned)mp[c & 1][1][r4][opx] << 16);
            float y  = dtanh2(fminf(f0, f1));
            const int oh = hbase + 4 * c + r4;
            const int ow = ow0 + opx;
            if (oh < OHH && ow < OWW)
                out[((size_t)n * OHH + oh) * OWW + ow] = y;
        }
    }
#undef ISSUE
#undef WRITEBK
}

extern "C" void kernel_launch(void* const* d_in, const int* in_sizes, int n_in,
                              void* d_out, int out_size, void* d_ws, size_t ws_size,
                              hipStream_t stream) {
    const float* x = (const float*)d_in[0];
    const float* w = (const float*)d_in[1];
    const float* b = (const float*)d_in[2];
    float* out     = (float*)d_out;
    ushort* wfrag  = (ushort*)d_ws;          // 18 KiB

    prep_weights<<<36, 256, 0, stream>>>(w, wfrag);
    dim3 grid(8, 3, 32);                     // (w-strip, 85-row strip, n): 768 blocks = 3/CU exact
    conv_min_tanh<<<grid, dim3(256, 1, 1), 0, stream>>>(x, wfrag, b, out);
}

// Round 22
// 52.011 us; speedup vs baseline: 1.0406x; 1.0406x over previous
//
#include <hip/hip_runtime.h>
#include <hip/hip_bf16.h>

typedef __attribute__((ext_vector_type(8)))  short short8;
typedef __attribute__((ext_vector_type(4)))  float f32x4;
typedef __attribute__((ext_vector_type(16))) float f32x16;

#define CIN   16
#define HH    256
#define WW    256
#define OHH   254
#define OWW   254
#define HW    (HH * WW)

// LDS row-ring: [2 cihalf][16 slot][36 w][8 ci] bf16, 16B cells (R7/R13-proven
// geometry: px stride 16B -> conflict-free b128). Half stride padded +16B.
#define SLOTU  (36 * 8)              // 288 ushorts per patch row
#define HALF_R (16 * SLOTU + 8)      // 4616 ushorts per ci-half
// ring = 18,464 B; + mp 1 KB -> ~19.5 KB LDS

__device__ __forceinline__ ushort f2bf(float f) {
    unsigned u = __builtin_bit_cast(unsigned, f);
    unsigned r = (u + 0x7fffu + ((u >> 16) & 1u)) >> 16;
    return (ushort)r;
}

// fast tanh(tanh(x)): exp2-based (verified absmax 3.9e-3 in R1-R21)
__device__ __forceinline__ float dtanh2(float x) {
    const float K = 2.8853900817779268f;   // 2*log2(e)
    float xc = fminf(fmaxf(x, -9.0f), 9.0f);
    float e1 = __builtin_amdgcn_exp2f(K * xc);
    float t1 = 1.0f - 2.0f * __builtin_amdgcn_rcpf(e1 + 1.0f);
    float e2 = __builtin_amdgcn_exp2f(K * t1);
    return 1.0f - 2.0f * __builtin_amdgcn_rcpf(e2 + 1.0f);
}

// Weights fp32 OIHW [64][16][3][3] -> 32x32x16 A-fragments (R9-proven):
// wfrag[tap][j][lane][r]: channel row = j*32+(lane&31), ci = 8*(lane>>5)+r.
__global__ void prep_weights(const float* __restrict__ wsrc, ushort* __restrict__ wfrag) {
    int idx = blockIdx.x * 256 + threadIdx.x;
    if (idx >= 9216) return;
    int r    = idx & 7;
    int lane = (idx >> 3) & 63;
    int j    = (idx >> 9) & 1;
    int tap  = idx >> 10;                 // 0..8
    int ci   = 8 * (lane >> 5) + r;
    int co   = j * 32 + (lane & 31);
    int kh   = tap / 3, kw = tap - 3 * kh;
    wfrag[idx] = f2bf(wsrc[(co * CIN + ci) * 9 + kh * 3 + kw]);
}

// Persistent half-strip kernel: 32 cols x 128 rows per block, 16-slot ring,
// 2-deep chunk prefetch with counted vmcnt(4) + RAW s_barrier (no vmcnt drain:
// __syncthreads emits vmcnt(0) before s_barrier -- that killed R14's pipeline).
// Best-measured structure of the session (R16: 51.85 us).
__global__ __launch_bounds__(256, 2) void conv_min_tanh(
        const float* __restrict__ x, const ushort* __restrict__ wfrag,
        const float* __restrict__ bias, float* __restrict__ out) {
    __shared__ ushort ring[2 * HALF_R];      // 18,464 B
    __shared__ ushort mp[2][2][4][32];       // 1,024 B (parity-double-buffered)

    const int tid   = threadIdx.x;
    const int ow0   = blockIdx.x * 32;
    const int hbase = blockIdx.y * 128;      // half-strip base row
    const int n     = blockIdx.z;
    const float* xb = x + (size_t)n * CIN * HW;

    // ---- prologue: stage patch rows hbase..hbase+7 (chunks 0,1) inline ----
    auto stage_inline = [&](int pos) {       // pos = lr*36 + ciq*9 + w4, lr 0..7
        int lr_  = pos / 36;
        int rm_  = pos - lr_ * 36;
        int ciq_ = rm_ / 9;
        int w4_  = rm_ - ciq_ * 9;
        int hg  = min(hbase + lr_, HH - 1);
        int wg_ = min(ow0 + 4 * w4_, WW - 4);
        const float* src = xb + (size_t)(ciq_ * 4) * HW + hg * WW + wg_;
        f32x4 v0 = *reinterpret_cast<const f32x4*>(src);
        f32x4 v1 = *reinterpret_cast<const f32x4*>(src + HW);
        f32x4 v2 = *reinterpret_cast<const f32x4*>(src + 2 * HW);
        f32x4 v3 = *reinterpret_cast<const f32x4*>(src + 3 * HW);
        ushort* dst = &ring[(ciq_ >> 1) * HALF_R + lr_ * SLOTU + (4 * w4_) * 8 + (ciq_ & 1) * 4];
#pragma unroll
        for (int e = 0; e < 4; ++e) {
            unsigned lo, hi;
            asm("v_cvt_pk_bf16_f32 %0, %1, %2" : "=v"(lo) : "v"(v0[e]), "v"(v1[e]));
            asm("v_cvt_pk_bf16_f32 %0, %1, %2" : "=v"(hi) : "v"(v2[e]), "v"(v3[e]));
            uint2 pk; pk.x = lo; pk.y = hi;
            *reinterpret_cast<uint2*>(dst + e * 8) = pk;
        }
    };
    stage_inline(tid);
    if (tid < 32) stage_inline(tid + 256);   // 288 positions = 8 rows

    // ---- steady-state stage constants (threads 0..143, 1 position each) ----
    const bool sa = (tid < 144);
    const int lr  = tid / 36;                // 0..3 within chunk
    const int rm  = tid - lr * 36;
    const int ciq = rm / 9;
    const int w4  = rm - ciq * 9;
    const int wg  = min(ow0 + 4 * w4, WW - 4);
    const float* gbase = xb + (size_t)(ciq * 4) * HW + wg;
    ushort* sdst = &ring[(ciq >> 1) * HALF_R + (4 * w4) * 8 + (ciq & 1) * 4];

    f32x4 ra0 = {}, ra1 = {}, ra2 = {}, ra3 = {};
    f32x4 rb0 = {}, rb1 = {}, rb2 = {}, rb3 = {};

#define ISSUE(cc, r0, r1, r2, r3)                                              \
    if (sa) {                                                                  \
        int hg = min(hbase + 4 * (cc) + lr, HH - 1);                           \
        const float* s_ = gbase + hg * WW;                                     \
        asm volatile("global_load_dwordx4 %0, %1, off" : "=v"(r0) : "v"(s_) : "memory");           \
        asm volatile("global_load_dwordx4 %0, %1, off" : "=v"(r1) : "v"(s_ + HW) : "memory");      \
        asm volatile("global_load_dwordx4 %0, %1, off" : "=v"(r2) : "v"(s_ + 2 * HW) : "memory");  \
        asm volatile("global_load_dwordx4 %0, %1, off" : "=v"(r3) : "v"(s_ + 3 * HW) : "memory");  \
    }

#define WRITEBK(cc, r0, r1, r2, r3)                                            \
    if (sa) {                                                                  \
        ushort* d_ = sdst + ((4 * (cc) + lr) & 15) * SLOTU;                    \
        _Pragma("unroll")                                                      \
        for (int e = 0; e < 4; ++e) {                                          \
            unsigned lo_, hi_;                                                 \
            asm("v_cvt_pk_bf16_f32 %0, %1, %2" : "=v"(lo_) : "v"(r0[e]), "v"(r1[e]));  \
            asm("v_cvt_pk_bf16_f32 %0, %1, %2" : "=v"(hi_) : "v"(r2[e]), "v"(r3[e]));  \
            uint2 pk_; pk_.x = lo_; pk_.y = hi_;                               \
            *reinterpret_cast<uint2*>(d_ + e * 8) = pk_;                       \
        }                                                                      \
    }

    ISSUE(2, ra0, ra1, ra2, ra3);            // 2-deep prefetch, 8 loads in flight
    ISSUE(3, rb0, rb1, rb2, rb3);

    // ---- weights (A-operand) + bias while loads fly ----
    const int lane  = tid & 63;
    const int wid   = tid >> 6;
    const int jw    = wid & 1;               // channel tile
    const int rq    = wid >> 1;              // row pair within chunk
    const int px    = lane & 31;
    const int khalf = lane >> 5;
    short8 wf[9];
#pragma unroll
    for (int tap = 0; tap < 9; ++tap)
        wf[tap] = *reinterpret_cast<const short8*>(wfrag + ((tap * 2 + jw) * 64 + lane) * 8);
    f32x16 bi;                               // D row = (r&3)+8*(r>>2)+4*khalf
#pragma unroll
    for (int q4 = 0; q4 < 4; ++q4) {
        f32x4 b = *reinterpret_cast<const f32x4*>(bias + jw * 32 + 4 * khalf + 8 * q4);
#pragma unroll
        for (int s = 0; s < 4; ++s) bi[q4 * 4 + s] = b[s];
    }
    const ushort* bptr = &ring[khalf * HALF_R + px * 8];

    asm volatile("s_waitcnt lgkmcnt(0)" ::: "memory");
    __builtin_amdgcn_s_barrier();            // rows 0..7 ready; loads stay in flight

    // ---- 32 chunks: compute(c) | vmcnt(4) write(c+2) issue(c+4) | barrier | out(c) ----
#pragma unroll 2
    for (int c = 0; c < 32; ++c) {
        // compute chunk c: out rows hbase + 4c + 2rq + jj
#pragma unroll
        for (int jj = 0; jj < 2; ++jj) {
            const int R = 4 * c + 2 * rq + jj;
            f32x16 a = bi;
#pragma unroll
            for (int kh = 0; kh < 3; ++kh) {
                const ushort* rp = bptr + ((R + kh) & 15) * SLOTU;
#pragma unroll
                for (int kw = 0; kw < 3; ++kw) {
                    short8 b = *reinterpret_cast<const short8*>(rp + kw * 8);
                    a = __builtin_amdgcn_mfma_f32_32x32x16_bf16(wf[kh * 3 + kw], b, a, 0, 0, 0);
                }
            }
            float v = a[0];
#pragma unroll
            for (int r = 1; r < 16; ++r) v = fminf(v, a[r]);
            v = fminf(v, __shfl_xor(v, 32, 64));
            if (lane < 32) mp[c & 1][jw][2 * rq + jj][px] = f2bf(v);
        }

        // drain ONLY the oldest chunk (counted vmcnt), write it, reissue
        if (c < 31) {
            if ((c & 1) == 0) {
                asm volatile("s_waitcnt vmcnt(4)"
                             : "+v"(ra0), "+v"(ra1), "+v"(ra2), "+v"(ra3) :: "memory");
                WRITEBK(c + 2, ra0, ra1, ra2, ra3);
                ISSUE(min(c + 4, 32), ra0, ra1, ra2, ra3);
            } else {
                asm volatile("s_waitcnt vmcnt(4)"
                             : "+v"(rb0), "+v"(rb1), "+v"(rb2), "+v"(rb3) :: "memory");
                WRITEBK(c + 2, rb0, rb1, rb2, rb3);
                ISSUE(min(c + 4, 32), rb0, rb1, rb2, rb3);
            }
        }

        asm volatile("s_waitcnt lgkmcnt(0)" ::: "memory");
        __builtin_amdgcn_s_barrier();        // NO vmcnt drain: pipeline survives

        // out(c): threads 0..127, one pixel each; mp parity c&1
        if (tid < 128) {
            const int r4 = tid >> 5, opx = tid & 31;
            float f0 = __builtin_bit_cast(float, (unsigned)mp[c & 1][0][r4][opx] << 16);
            float f1 = __builtin_bit_cast(float, (unsigned)mp[c & 1][1][r4][opx] << 16);
            float y  = dtanh2(fminf(f0, f1));
            const int oh = hbase + 4 * c + r4;
            const int ow = ow0 + opx;
            if (oh < OHH && ow < OWW)
                out[((size_t)n * OHH + oh) * OWW + ow] = y;
        }
    }
#undef ISSUE
#undef WRITEBK
}

extern "C" void kernel_launch(void* const* d_in, const int* in_sizes, int n_in,
                              void* d_out, int out_size, void* d_ws, size_t ws_size,
                              hipStream_t stream) {
    const float* x = (const float*)d_in[0];
    const float* w = (const float*)d_in[1];
    const float* b = (const float*)d_in[2];
    float* out     = (float*)d_out;
    ushort* wfrag  = (ushort*)d_ws;          // 18 KiB

    prep_weights<<<36, 256, 0, stream>>>(w, wfrag);
    dim3 grid(8, 2, 32);                     // (w-strip, h-half, n): 512 blocks, 2/CU
    conv_min_tanh<<<grid, dim3(256, 1, 1), 0, stream>>>(x, wfrag, b, out);
}